// Round 17
// baseline (710.856 us; speedup 1.0000x reference)
//
#include <hip/hip_runtime.h>

#define B_ROWS 8192
#define DDIM 2048
#define NEXP 8
#define NASSIGN (B_ROWS * 2)
#define MAX_TILES 80

typedef unsigned short u16;
typedef short bf16x8 __attribute__((ext_vector_type(8)));
typedef float f32x4 __attribute__((ext_vector_type(4)));

// meta int layout: [0..7]=cnt [8..15]=fill [16..23]=segstart
//                  [32..111]=tile_e [112..191]=tile_base [192..271]=tile_rem
#define M_CNT 0
#define M_FILL 8
#define M_SEG 16
#define M_TE 32
#define M_TB 112
#define M_TR 192

__device__ __forceinline__ u16 f2b(float f) {
  union { float f; unsigned u; } c; c.f = f;
  return (u16)((c.u + 0x7fffu + ((c.u >> 16) & 1u)) >> 16);
}
__device__ __forceinline__ float b2f(u16 h) {
  union { unsigned u; float f; } c; c.u = ((unsigned)h) << 16;
  return c.f;
}
__device__ __forceinline__ void async16(u16* lds, const u16* g) {
  __builtin_amdgcn_global_load_lds(
      (const __attribute__((address_space(1))) unsigned int*)g,
      (__attribute__((address_space(3))) unsigned int*)lds, 16, 0, 0);
}

__global__ void init_meta_kernel(int* meta) {
  int t = threadIdx.x;
  if (t < 32) meta[t] = 0;
}

// ---------------------------------------------------------------------------
// Pass A: streaming sum+convert, NATURAL layout (no transpose, no LDS).
// Wsum[e][k][n] = bf16(sum_c Wqkv[e][k][c*2048+n]); WprojN = bf16(Wp).
// Pure grid-stride float4->uint4: must run at streaming BW.
// ---------------------------------------------------------------------------
__global__ __launch_bounds__(256) void sumcvt_kernel(
    const float* __restrict__ Wqkv, const float* __restrict__ Wp,
    u16* __restrict__ Wsum, u16* __restrict__ WprojN) {
  const long long NV_E = (long long)NEXP * 2048 * 256;  // expert vec8 count
  const long long NV_P = 2048 * 256;                    // proj vec8 count
  long long v = (long long)blockIdx.x * 256 + threadIdx.x;
  const long long stride = (long long)gridDim.x * 256;
  for (; v < NV_E + NV_P; v += stride) {
    float s[8];
    u16* dst;
    if (v < NV_E) {
      int e = (int)(v >> 19);
      int rem = (int)(v & 524287);
      int k = rem >> 8, nc = rem & 255;
      const float* p = Wqkv + (size_t)e * 2048 * 6144 + (size_t)k * 6144 + nc * 8;
      float4 a0 = *(const float4*)p, a1 = *(const float4*)(p + 4);
      float4 b0 = *(const float4*)(p + 2048), b1 = *(const float4*)(p + 2052);
      float4 c0 = *(const float4*)(p + 4096), c1 = *(const float4*)(p + 4100);
      s[0] = a0.x + b0.x + c0.x; s[1] = a0.y + b0.y + c0.y;
      s[2] = a0.z + b0.z + c0.z; s[3] = a0.w + b0.w + c0.w;
      s[4] = a1.x + b1.x + c1.x; s[5] = a1.y + b1.y + c1.y;
      s[6] = a1.z + b1.z + c1.z; s[7] = a1.w + b1.w + c1.w;
      dst = Wsum + ((size_t)e * 2048 + k) * 2048 + nc * 8;
    } else {
      int rem = (int)(v - NV_E);
      int k = rem >> 8, nc = rem & 255;
      const float* p = Wp + (size_t)k * 2048 + nc * 8;
      float4 a0 = *(const float4*)p, a1 = *(const float4*)(p + 4);
      s[0] = a0.x; s[1] = a0.y; s[2] = a0.z; s[3] = a0.w;
      s[4] = a1.x; s[5] = a1.y; s[6] = a1.z; s[7] = a1.w;
      dst = WprojN + (size_t)k * 2048 + nc * 8;
    }
    uint4 pk;
    pk.x = (unsigned)f2b(s[0]) | ((unsigned)f2b(s[1]) << 16);
    pk.y = (unsigned)f2b(s[2]) | ((unsigned)f2b(s[3]) << 16);
    pk.z = (unsigned)f2b(s[4]) | ((unsigned)f2b(s[5]) << 16);
    pk.w = (unsigned)f2b(s[6]) | ((unsigned)f2b(s[7]) << 16);
    *(uint4*)dst = pk;
  }
}

// ---------------------------------------------------------------------------
// Pass B: bf16 transpose [k][n] -> [n][k], 128x128 tiles, padded LDS
// ([128][136]: 16B-aligned rows, column reads 4-way max). Input is
// L3-resident (just written by pass A) -> scattered reads hit L3 not DRAM.
// XCD chunk swizzle (2304 = 8*288).
// ---------------------------------------------------------------------------
__global__ __launch_bounds__(256) void transpose_kernel(
    const u16* __restrict__ Wsum, const u16* __restrict__ WprojN,
    u16* __restrict__ WsumT, u16* __restrict__ WprojT) {
  __shared__ __align__(16) u16 tl[128][136];
  const int orig = blockIdx.x;
  const int bid = (orig & 7) * 288 + (orig >> 3);
  const u16* src;
  u16* dst;
  int tk, tn;
  if (bid < 2048) {
    int e = bid >> 8, tile = bid & 255;
    tk = tile >> 4; tn = tile & 15;
    src = Wsum + (size_t)e * 2048 * 2048;
    dst = WsumT + (size_t)e * 2048 * 2048;
  } else {
    int tile = bid - 2048;
    tk = tile >> 4; tn = tile & 15;
    src = WprojN;
    dst = WprojT;
  }
  const int k0 = tk * 128, n0 = tn * 128;
  const int t = threadIdx.x;
#pragma unroll
  for (int i = 0; i < 8; ++i) {
    int idx = i * 256 + t;
    int r = idx >> 4, c = idx & 15;
    *(uint4*)&tl[r][c * 8] =
        *(const uint4*)(src + (size_t)(k0 + r) * 2048 + n0 + c * 8);
  }
  __syncthreads();
#pragma unroll
  for (int i = 0; i < 8; ++i) {
    int idx = i * 256 + t;
    int n = idx & 127, kc = idx >> 7;  // lanes span n -> conflict-free cols
    u16 r8[8];
#pragma unroll
    for (int j = 0; j < 8; ++j) r8[j] = tl[kc * 8 + j][n];
    uint4 pk;
    pk.x = (unsigned)r8[0] | ((unsigned)r8[1] << 16);
    pk.y = (unsigned)r8[2] | ((unsigned)r8[3] << 16);
    pk.z = (unsigned)r8[4] | ((unsigned)r8[5] << 16);
    pk.w = (unsigned)r8[6] | ((unsigned)r8[7] << 16);
    *(uint4*)(dst + (size_t)(n0 + n) * 2048 + k0 + kc * 8) = pk;
  }
}

// Gate: per-row logits (f64 accum), softmax, top-2; also converts x -> bf16.
__global__ __launch_bounds__(256) void gate_kernel(
    const float* __restrict__ x, const float* __restrict__ Wg,
    const float* __restrict__ bg, u16* __restrict__ xb,
    int* __restrict__ e01, float* __restrict__ w01, int* __restrict__ meta) {
  int b = blockIdx.x, t = threadIdx.x;
  const float* xr = x + (size_t)b * DDIM;
  float4 v0 = ((const float4*)xr)[2 * t];
  float4 v1 = ((const float4*)xr)[2 * t + 1];
  float xv[8] = {v0.x, v0.y, v0.z, v0.w, v1.x, v1.y, v1.z, v1.w};
  uint4 pk;
  pk.x = (unsigned)f2b(xv[0]) | ((unsigned)f2b(xv[1]) << 16);
  pk.y = (unsigned)f2b(xv[2]) | ((unsigned)f2b(xv[3]) << 16);
  pk.z = (unsigned)f2b(xv[4]) | ((unsigned)f2b(xv[5]) << 16);
  pk.w = (unsigned)f2b(xv[6]) | ((unsigned)f2b(xv[7]) << 16);
  *(uint4*)(xb + (size_t)b * DDIM + t * 8) = pk;

  double acc[8] = {0, 0, 0, 0, 0, 0, 0, 0};
#pragma unroll
  for (int j = 0; j < 8; ++j) {
    const float4* wr = (const float4*)(Wg + (size_t)(t * 8 + j) * 8);
    float4 wa = wr[0], wb = wr[1];
    double xd = (double)xv[j];
    acc[0] += xd * wa.x; acc[1] += xd * wa.y;
    acc[2] += xd * wa.z; acc[3] += xd * wa.w;
    acc[4] += xd * wb.x; acc[5] += xd * wb.y;
    acc[6] += xd * wb.z; acc[7] += xd * wb.w;
  }
#pragma unroll
  for (int e = 0; e < 8; ++e)
    for (int m2 = 32; m2; m2 >>= 1) acc[e] += __shfl_xor(acc[e], m2);
  __shared__ double red[4][8];
  if ((t & 63) == 0)
    for (int e = 0; e < 8; ++e) red[t >> 6][e] = acc[e];
  __syncthreads();
  if (t == 0) {
    double l[8];
    for (int e = 0; e < 8; ++e)
      l[e] = red[0][e] + red[1][e] + red[2][e] + red[3][e] + (double)bg[e];
    double mx = l[0];
    for (int e = 1; e < 8; ++e) mx = l[e] > mx ? l[e] : mx;
    double p[8], s = 0;
    for (int e = 0; e < 8; ++e) { p[e] = exp(l[e] - mx); s += p[e]; }
    int i1 = 0;
    for (int e = 1; e < 8; ++e) if (p[e] > p[i1]) i1 = e;
    int i2 = (i1 == 0) ? 1 : 0;
    for (int e = 0; e < 8; ++e)
      if (e != i1 && p[e] > p[i2]) i2 = e;
    e01[2 * b] = i1; e01[2 * b + 1] = i2;
    w01[2 * b] = (float)(p[i1] / s);
    w01[2 * b + 1] = (float)(p[i2] / s);
    atomicAdd(&meta[M_CNT + i1], 1);
    atomicAdd(&meta[M_CNT + i2], 1);
  }
}

// Wave-parallel scan, 256-row tile granularity.
__global__ __launch_bounds__(128) void scan_kernel(int* meta) {
  __shared__ int scnt[8];
  int t = threadIdx.x;
  if (t < 8) scnt[t] = meta[M_CNT + t];
  __syncthreads();
  int seg[9], pre[9];
  seg[0] = 0; pre[0] = 0;
#pragma unroll
  for (int e = 0; e < 8; ++e) {
    seg[e + 1] = seg[e] + scnt[e];
    pre[e + 1] = pre[e] + ((scnt[e] + 255) >> 8);
  }
  if (t < 8) meta[M_SEG + t] = seg[t];
  if (t < MAX_TILES) {
    if (t < pre[8]) {
      int e = 0;
      while (e < 7 && t >= pre[e + 1]) ++e;
      int i = t - pre[e];
      meta[M_TE + t] = e;
      meta[M_TB + t] = seg[e] + i * 256;
      meta[M_TR + t] = scnt[e] - i * 256;
    } else {
      meta[M_TE + t] = 0; meta[M_TB + t] = 0; meta[M_TR + t] = 0;
    }
  }
}

__global__ __launch_bounds__(256) void build_kernel(
    const int* __restrict__ e01, const float* __restrict__ w01,
    int* __restrict__ meta, int* __restrict__ rows, float* __restrict__ wt,
    int* __restrict__ rowpos) {
  int b = blockIdx.x * 256 + threadIdx.x;
  if (b >= B_ROWS) return;
#pragma unroll
  for (int s = 0; s < 2; ++s) {
    int e = e01[2 * b + s];
    float w = w01[2 * b + s];
    int p = meta[M_SEG + e] + atomicAdd(&meta[M_FILL + e], 1);
    rows[p] = b;
    wt[p] = w;
    rowpos[2 * b + s] = p;
  }
}

// ---------------------------------------------------------------------------
// 256x256 8-phase MFMA GEMM — R2-exact (best measured: expert 189us).
// ---------------------------------------------------------------------------
#define BAR()                           \
  do {                                  \
    __builtin_amdgcn_sched_barrier(0);  \
    __builtin_amdgcn_s_barrier();       \
    __builtin_amdgcn_sched_barrier(0);  \
  } while (0)
#define VMCNT2() asm volatile("s_waitcnt vmcnt(2)" ::: "memory")
#define VMCNT0() asm volatile("s_waitcnt vmcnt(0)" ::: "memory")
#define LGKM0()                                       \
  do {                                                \
    asm volatile("s_waitcnt lgkmcnt(0)" ::: "memory"); \
    __builtin_amdgcn_sched_barrier(0);                \
  } while (0)

#define STAGE_A(L, T, BB) async16(&lds[BB][0][(L)*4096 + t * 8], srcA[L] + (size_t)(T)*64)
#define STAGE_B(L, T, BB) async16(&lds[BB][1][(L)*4096 + t * 8], srcB[L] + (size_t)(T)*64)

#define READ_A(QM)                                                   \
  do {                                                               \
    _Pragma("unroll") for (int i_ = 0; i_ < 4; ++i_) {               \
      int rb_ = baseA + ((QM)*64 + i_ * 16) * 128;                   \
      af[i_][0] = *(const bf16x8*)(pA + rb_ + ck0);                  \
      af[i_][1] = *(const bf16x8*)(pA + rb_ + ck1);                  \
    }                                                                \
  } while (0)
#define READ_B(H)                                                    \
  do {                                                               \
    _Pragma("unroll") for (int j_ = 0; j_ < 2; ++j_) {               \
      int rb_ = baseB + (((H)*2 + j_) * 16) * 128;                   \
      bfr[(H)*2 + j_][0] = *(const bf16x8*)(pB + rb_ + ck0);         \
      bfr[(H)*2 + j_][1] = *(const bf16x8*)(pB + rb_ + ck1);         \
    }                                                                \
  } while (0)
#define MFMA16(QM, QN)                                                         \
  do {                                                                         \
    _Pragma("unroll") for (int i_ = 0; i_ < 4; ++i_) {                         \
      _Pragma("unroll") for (int j_ = 0; j_ < 2; ++j_) {                       \
        acc[(QM)*4 + i_][(QN)*2 + j_] = __builtin_amdgcn_mfma_f32_16x16x32_bf16( \
            af[i_][0], bfr[(QN)*2 + j_][0], acc[(QM)*4 + i_][(QN)*2 + j_], 0, 0, 0); \
        acc[(QM)*4 + i_][(QN)*2 + j_] = __builtin_amdgcn_mfma_f32_16x16x32_bf16( \
            af[i_][1], bfr[(QN)*2 + j_][1], acc[(QM)*4 + i_][(QN)*2 + j_], 0, 0, 0); \
      }                                                                        \
    }                                                                          \
  } while (0)

template <int MODE>
__global__ __launch_bounds__(512, 2) void gemm256_kernel(
    const u16* __restrict__ A, const u16* __restrict__ BT,
    const int* __restrict__ meta, const int* __restrict__ rows,
    const float* __restrict__ wt, const float* __restrict__ bias,
    u16* __restrict__ Yc, float* __restrict__ Out) {
  __shared__ __align__(16) u16 lds[2][2][16384];  // [buf][A/B][256*64]

  int e = 0, base = 0, rem = 256, m0 = 0;
  if (MODE == 0) {
    rem = meta[M_TR + blockIdx.y];
    if (rem <= 0) return;
    if (rem > 256) rem = 256;
    e = meta[M_TE + blockIdx.y];
    base = meta[M_TB + blockIdx.y];
  } else {
    m0 = blockIdx.y * 256;
  }
  const int n0 = blockIdx.x * 256;
  const int t = threadIdx.x;
  const int lane = t & 63;
  const int wid = t >> 6;
  const int wr = wid >> 2, wc = wid & 3;
  const int l15 = lane & 15;
  const int kg = lane >> 4;
  const int sw = lane & 7;

  const u16* srcA[4];
  const u16* srcB[4];
#pragma unroll
  for (int L = 0; L < 4; ++L) {
    int row = L * 64 + (t >> 3);
    int cl = (t & 7) ^ (row & 7);
    int grow;
    if (MODE == 0) {
      int rl = row < rem ? row : 0;
      grow = rows[base + rl];
    } else {
      grow = m0 + row;
    }
    srcA[L] = A + (size_t)grow * DDIM + cl * 8;
    srcB[L] = BT + ((size_t)e * DDIM + n0 + row) * DDIM + cl * 8;
  }

  f32x4 acc[8][4];
#pragma unroll
  for (int i = 0; i < 8; ++i)
#pragma unroll
    for (int j = 0; j < 4; ++j) {
      f32x4 z = {0.f, 0.f, 0.f, 0.f};
      acc[i][j] = z;
    }

  const int baseA = (wr * 128 + l15) * 128;
  const int baseB = (wc * 64 + l15) * 128;
  const int ck0 = ((0 * 4 + kg) ^ sw) << 4;
  const int ck1 = ((1 * 4 + kg) ^ sw) << 4;

  bf16x8 af[4][2];
  bf16x8 bfr[4][2];

  STAGE_A(0, 0, 0); STAGE_A(1, 0, 0); STAGE_A(2, 0, 0); STAGE_A(3, 0, 0);
  STAGE_B(0, 0, 0); STAGE_B(1, 0, 0); STAGE_B(2, 0, 0); STAGE_B(3, 0, 0);
  STAGE_A(0, 1, 1); STAGE_A(1, 1, 1);
  VMCNT2();
  BAR();

  const int NT = DDIM / 64;
  for (int T = 0; T < NT; ++T) {
    const int cb = T & 1, nb = cb ^ 1;
    const char* pA = (const char*)&lds[cb][0][0];
    const char* pB = (const char*)&lds[cb][1][0];
    READ_A(0);
    READ_B(0);
    if (T + 1 < NT) { STAGE_A(2, T + 1, nb); STAGE_A(3, T + 1, nb); }
    BAR();
    LGKM0();
    __builtin_amdgcn_s_setprio(1);
    MFMA16(0, 0);
    __builtin_amdgcn_s_setprio(0);
    BAR();
    READ_B(1);
    if (T + 1 < NT) { STAGE_B(0, T + 1, nb); STAGE_B(1, T + 1, nb); }
    BAR();
    LGKM0();
    __builtin_amdgcn_s_setprio(1);
    MFMA16(0, 1);
    __builtin_amdgcn_s_setprio(0);
    BAR();
    READ_A(1);
    if (T + 1 < NT) { STAGE_B(2, T + 1, nb); STAGE_B(3, T + 1, nb); }
    BAR();
    LGKM0();
    __builtin_amdgcn_s_setprio(1);
    MFMA16(1, 0);
    __builtin_amdgcn_s_setprio(0);
    BAR();
    if (T + 2 < NT) {
      STAGE_A(0, T + 2, cb); STAGE_A(1, T + 2, cb);
      VMCNT2();
    } else {
      VMCNT0();
    }
    BAR();
    __builtin_amdgcn_s_setprio(1);
    MFMA16(1, 1);
    __builtin_amdgcn_s_setprio(0);
    BAR();
  }

  if (MODE == 1) {
    float bv[4];
#pragma unroll
    for (int fn = 0; fn < 4; ++fn) bv[fn] = bias[n0 + wc * 64 + fn * 16 + l15];
#pragma unroll
    for (int qm = 0; qm < 2; ++qm)
#pragma unroll
      for (int i = 0; i < 4; ++i)
#pragma unroll
        for (int r = 0; r < 4; ++r) {
          int rl = wr * 128 + qm * 64 + i * 16 + kg * 4 + r;
          float* orow = Out + (size_t)(m0 + rl) * DDIM + n0 + wc * 64 + l15;
#pragma unroll
          for (int fn = 0; fn < 4; ++fn)
            orow[fn * 16] = acc[qm * 4 + i][fn][r] + bv[fn];
        }
  } else {
#pragma unroll
    for (int qm = 0; qm < 2; ++qm)
#pragma unroll
      for (int i = 0; i < 4; ++i)
#pragma unroll
        for (int r = 0; r < 4; ++r) {
          int rl = wr * 128 + qm * 64 + i * 16 + kg * 4 + r;
          if (rl < rem) {
            int pos = base + rl;
            float w = wt[pos];
            u16* yrow = Yc + (size_t)pos * DDIM + n0 + wc * 64 + l15;
#pragma unroll
            for (int fn = 0; fn < 4; ++fn)
              yrow[fn * 16] = f2b(w * acc[qm * 4 + i][fn][r]);
          }
        }
  }
}

// ---------------------------------------------------------------------------
// Combine + 16x16 self-attention per row, MFMA version (R9-exact).
// ---------------------------------------------------------------------------
__global__ __launch_bounds__(64) void combine_attn_kernel(
    const u16* __restrict__ Yc, const int* __restrict__ rowpos,
    u16* __restrict__ ab) {
  __shared__ __align__(16) u16 sb[16][136];
  __shared__ __align__(16) u16 pl[16][20];
  const int b = blockIdx.x, l = threadIdx.x;
  const int p0 = rowpos[2 * b], p1 = rowpos[2 * b + 1];
  const uint4* r0 = (const uint4*)(Yc + (size_t)p0 * DDIM + l * 32);
  const uint4* r1 = (const uint4*)(Yc + (size_t)p1 * DDIM + l * 32);
  {
    const int h = l >> 2, cbase = (l & 3) * 32;
#pragma unroll
    for (int q = 0; q < 4; ++q) {
      uint4 a = r0[q], c = r1[q];
      const unsigned* au = (const unsigned*)&a;
      const unsigned* cu = (const unsigned*)&c;
      uint4 w;
      unsigned* wu = (unsigned*)&w;
#pragma unroll
      for (int j = 0; j < 4; ++j) {
        float lo = b2f((u16)(au[j] & 0xffff)) + b2f((u16)(cu[j] & 0xffff));
        float hi = b2f((u16)(au[j] >> 16)) + b2f((u16)(cu[j] >> 16));
        wu[j] = (unsigned)f2b(lo) | ((unsigned)f2b(hi) << 16);
      }
      *(uint4*)&sb[h][cbase + q * 8] = w;
    }
  }
  __syncthreads();
  const int hh = l & 15, kg = l >> 4;
  f32x4 S = {0.f, 0.f, 0.f, 0.f};
#pragma unroll
  for (int kc = 0; kc < 4; ++kc) {
    bf16x8 f = *(const bf16x8*)&sb[hh][kc * 32 + kg * 8];
    S = __builtin_amdgcn_mfma_f32_16x16x32_bf16(f, f, S, 0, 0, 0);
  }
  const float sc = 0.088388347648318447f;
  float lg[4];
  float mx = -1e30f;
#pragma unroll
  for (int r = 0; r < 4; ++r) { lg[r] = S[r] * sc; mx = fmaxf(mx, lg[r]); }
  mx = fmaxf(mx, __shfl_xor(mx, 16));
  mx = fmaxf(mx, __shfl_xor(mx, 32));
  float p[4], sum = 0.f;
#pragma unroll
  for (int r = 0; r < 4; ++r) { p[r] = expf(lg[r] - mx); sum += p[r]; }
  sum += __shfl_xor(sum, 16);
  sum += __shfl_xor(sum, 32);
  const float inv = 1.f / sum;
#pragma unroll
  for (int r = 0; r < 4; ++r) pl[hh][kg * 4 + r] = f2b(p[r] * inv);
  __syncthreads();
  bf16x8 pa = {0, 0, 0, 0, 0, 0, 0, 0};
  if (kg < 2) pa = *(const bf16x8*)&pl[hh][kg * 8];
  u16* orow = ab + (size_t)b * DDIM;
#pragma unroll
  for (int c = 0; c < 8; ++c) {
    bf16x8 bv = {0, 0, 0, 0, 0, 0, 0, 0};
    if (kg < 2) {
      u16* bvp = (u16*)&bv;
#pragma unroll
      for (int j = 0; j < 8; ++j) bvp[j] = sb[kg * 8 + j][c * 16 + hh];
    }
    f32x4 z = {0.f, 0.f, 0.f, 0.f};
    f32x4 o = __builtin_amdgcn_mfma_f32_16x16x32_bf16(pa, bv, z, 0, 0, 0);
    uint2 st;
    st.x = (unsigned)f2b(o[0]) | ((unsigned)f2b(o[1]) << 16);
    st.y = (unsigned)f2b(o[2]) | ((unsigned)f2b(o[3]) << 16);
    *(uint2*)(orow + (c * 16 + hh) * 16 + kg * 4) = st;
  }
}

extern "C" void kernel_launch(void* const* d_in, const int* in_sizes, int n_in,
                              void* d_out, int out_size, void* d_ws, size_t ws_size,
                              hipStream_t stream) {
  const float* x = (const float*)d_in[0];
  const float* Wqkv = (const float*)d_in[1];
  const float* Wg = (const float*)d_in[2];
  const float* bg = (const float*)d_in[3];
  const float* Wp = (const float*)d_in[4];
  const float* bp = (const float*)d_in[5];
  float* out = (float*)d_out;

  char* ws = (char*)d_ws;
  size_t off = 0;
  auto alloc = [&](size_t bytes) {
    void* p = ws + off;
    off += (bytes + 255) & ~(size_t)255;
    return p;
  };
  u16* xb = (u16*)alloc((size_t)B_ROWS * DDIM * 2);
  u16* WsumT = (u16*)alloc((size_t)NEXP * DDIM * DDIM * 2);
  u16* WprojT = (u16*)alloc((size_t)DDIM * DDIM * 2);
  u16* Wsum = (u16*)alloc((size_t)NEXP * DDIM * DDIM * 2);
  u16* WprojN = (u16*)alloc((size_t)DDIM * DDIM * 2);
  u16* Yc = (u16*)alloc((size_t)NASSIGN * DDIM * 2);
  u16* ab = (u16*)alloc((size_t)B_ROWS * DDIM * 2);
  int* e01 = (int*)alloc((size_t)NASSIGN * 4);
  float* w01 = (float*)alloc((size_t)NASSIGN * 4);
  int* rows = (int*)alloc((size_t)NASSIGN * 4);
  float* wt = (float*)alloc((size_t)NASSIGN * 4);
  int* rowpos = (int*)alloc((size_t)NASSIGN * 4);
  int* meta = (int*)alloc(4096);

  init_meta_kernel<<<dim3(1), dim3(64), 0, stream>>>(meta);
  gate_kernel<<<dim3(B_ROWS), dim3(256), 0, stream>>>(x, Wg, bg, xb, e01, w01, meta);
  scan_kernel<<<dim3(1), dim3(128), 0, stream>>>(meta);
  build_kernel<<<dim3(32), dim3(256), 0, stream>>>(e01, w01, meta, rows, wt, rowpos);
  sumcvt_kernel<<<dim3(2048), dim3(256), 0, stream>>>(Wqkv, Wp, Wsum, WprojN);
  transpose_kernel<<<dim3(2304), dim3(256), 0, stream>>>(Wsum, WprojN, WsumT, WprojT);
  gemm256_kernel<0><<<dim3(8, MAX_TILES), dim3(512), 0, stream>>>(
      xb, WsumT, meta, rows, wt, nullptr, Yc, nullptr);
  combine_attn_kernel<<<dim3(B_ROWS), dim3(64), 0, stream>>>(Yc, rowpos, ab);
  gemm256_kernel<1><<<dim3(8, 32), dim3(512), 0, stream>>>(
      ab, WprojT, meta, rows, wt, bp, nullptr, out);
  (void)in_sizes; (void)n_in; (void)out_size; (void)ws_size;
}

// Round 18
// 587.249 us; speedup vs baseline: 1.2105x; 1.2105x over previous
//
#include <hip/hip_runtime.h>

#define B_ROWS 8192
#define DDIM 2048
#define NEXP 8
#define NASSIGN (B_ROWS * 2)
#define MAX_TILES 80
#define KBLK 131072  // 2048 n * 64 k elements per K-panel in blocked B layout

typedef unsigned short u16;
typedef short bf16x8 __attribute__((ext_vector_type(8)));
typedef float f32x4 __attribute__((ext_vector_type(4)));

// meta int layout: [0..7]=cnt [8..15]=fill [16..23]=segstart
//                  [32..111]=tile_e [112..191]=tile_base [192..271]=tile_rem
#define M_CNT 0
#define M_FILL 8
#define M_SEG 16
#define M_TE 32
#define M_TB 112
#define M_TR 192

__device__ __forceinline__ u16 f2b(float f) {
  union { float f; unsigned u; } c; c.f = f;
  return (u16)((c.u + 0x7fffu + ((c.u >> 16) & 1u)) >> 16);
}
__device__ __forceinline__ float b2f(u16 h) {
  union { unsigned u; float f; } c; c.u = ((unsigned)h) << 16;
  return c.f;
}
__device__ __forceinline__ void async16(u16* lds, const u16* g) {
  __builtin_amdgcn_global_load_lds(
      (const __attribute__((address_space(1))) unsigned int*)g,
      (__attribute__((address_space(3))) unsigned int*)lds, 16, 0, 0);
}

__global__ void init_meta_kernel(int* meta) {
  int t = threadIdx.x;
  if (t < 32) meta[t] = 0;
}

// ---------------------------------------------------------------------------
// Fused prologue: [0,8192) prep3 | [8192,9216) prep1 | [9216,17408) gate.
// R18: output in K-BLOCKED layout [e][kt][n][64k] -> each block's write is
// one 8KB contiguous span (thread t writes 32B at n=t>>2,kc=t&3). R14's
// [n][k] writes were 128B @ 4KB stride - same scatter pathology as reads.
// Reads keep R14's best-measured structure (async16 + XCD chunk swizzle).
// ---------------------------------------------------------------------------
__global__ __launch_bounds__(256) void prologue_kernel(
    const float* __restrict__ x, const float* __restrict__ Wqkv,
    const float* __restrict__ Wg, const float* __restrict__ bg,
    const float* __restrict__ Wp, u16* __restrict__ xb,
    u16* __restrict__ WsumT, u16* __restrict__ WprojT,
    int* __restrict__ e01, float* __restrict__ w01, int* __restrict__ meta) {
  __shared__ __align__(16) float ldsF[3][64][64];  // 48KB raw f32 staging
  __shared__ double red[4][8];
  const int orig = blockIdx.x;
  const int bid = (orig & 7) * 2176 + (orig >> 3);  // XCD chunk swizzle
  const int t = threadIdx.x;

  if (bid < 9216) {
    const float* Win;
    u16* Wout;
    int ldin, nsum, bx;
    if (bid < 8192) { Win = Wqkv; Wout = WsumT; ldin = 3 * DDIM; nsum = 3; bx = bid; }
    else            { Win = Wp;   Wout = WprojT; ldin = DDIM;    nsum = 1; bx = bid - 8192; }
    int nt = bx & 31, kt = (bx >> 5) & 31, e = bx >> 10;
    const size_t in_base = (size_t)e * DDIM * (size_t)ldin;
    int k0 = kt * 64, n0 = nt * 64;
    // --- phase 1: async global->LDS (fire-and-forget, full ILP) ---
    for (int ci = 0; ci < nsum; ++ci) {
#pragma unroll
      for (int i = 0; i < 4; ++i) {
        int idx = i * 256 + t;
        int kl = idx >> 4, f4 = idx & 15;
        const float* p =
            Win + in_base + (size_t)(k0 + kl) * ldin + ci * 2048 + n0 + f4 * 4;
        async16((u16*)&ldsF[ci][kl][f4 * 4], (const u16*)p);
      }
    }
    __syncthreads();  // compiler emits vmcnt(0) drain
    // --- phase 2: sum + convert + CONTIGUOUS blocked write ---
    // out[e][kt][n][64k]: thread t -> n = t>>2, kc = t&3 (16 k's), 32B store.
    u16* out = Wout + ((size_t)e * 32 + kt) * KBLK;
    {
      int n = t >> 2, kc = t & 3;
      u16 r[16];
#pragma unroll
      for (int j = 0; j < 16; ++j) {
        int k = kc * 16 + j;
        float v = ldsF[0][k][n];
        if (nsum == 3) v += ldsF[1][k][n] + ldsF[2][k][n];
        r[j] = f2b(v);
      }
      uint4 pk0, pk1;
      pk0.x = (unsigned)r[0] | ((unsigned)r[1] << 16);
      pk0.y = (unsigned)r[2] | ((unsigned)r[3] << 16);
      pk0.z = (unsigned)r[4] | ((unsigned)r[5] << 16);
      pk0.w = (unsigned)r[6] | ((unsigned)r[7] << 16);
      pk1.x = (unsigned)r[8] | ((unsigned)r[9] << 16);
      pk1.y = (unsigned)r[10] | ((unsigned)r[11] << 16);
      pk1.z = (unsigned)r[12] | ((unsigned)r[13] << 16);
      pk1.w = (unsigned)r[14] | ((unsigned)r[15] << 16);
      u16* op = out + (size_t)(n0 + n) * 64 + kc * 16;
      *(uint4*)op = pk0;
      *(uint4*)(op + 8) = pk1;
    }
    return;
  }

  // ---- gate + x->bf16 ----
  const int b = bid - 9216;
  const float* xr = x + (size_t)b * DDIM;
  float4 v0 = ((const float4*)xr)[2 * t];
  float4 v1 = ((const float4*)xr)[2 * t + 1];
  float xv[8] = {v0.x, v0.y, v0.z, v0.w, v1.x, v1.y, v1.z, v1.w};
  uint4 pk;
  pk.x = (unsigned)f2b(xv[0]) | ((unsigned)f2b(xv[1]) << 16);
  pk.y = (unsigned)f2b(xv[2]) | ((unsigned)f2b(xv[3]) << 16);
  pk.z = (unsigned)f2b(xv[4]) | ((unsigned)f2b(xv[5]) << 16);
  pk.w = (unsigned)f2b(xv[6]) | ((unsigned)f2b(xv[7]) << 16);
  *(uint4*)(xb + (size_t)b * DDIM + t * 8) = pk;

  double acc[8] = {0, 0, 0, 0, 0, 0, 0, 0};
#pragma unroll
  for (int j = 0; j < 8; ++j) {
    const float4* wr = (const float4*)(Wg + (size_t)(t * 8 + j) * 8);
    float4 wa = wr[0], wb = wr[1];
    double xd = (double)xv[j];
    acc[0] += xd * wa.x; acc[1] += xd * wa.y;
    acc[2] += xd * wa.z; acc[3] += xd * wa.w;
    acc[4] += xd * wb.x; acc[5] += xd * wb.y;
    acc[6] += xd * wb.z; acc[7] += xd * wb.w;
  }
#pragma unroll
  for (int e = 0; e < 8; ++e)
    for (int m2 = 32; m2; m2 >>= 1) acc[e] += __shfl_xor(acc[e], m2);
  if ((t & 63) == 0)
    for (int e = 0; e < 8; ++e) red[t >> 6][e] = acc[e];
  __syncthreads();
  if (t == 0) {
    double l[8];
    for (int e = 0; e < 8; ++e)
      l[e] = red[0][e] + red[1][e] + red[2][e] + red[3][e] + (double)bg[e];
    double mx = l[0];
    for (int e = 1; e < 8; ++e) mx = l[e] > mx ? l[e] : mx;
    double p[8], s = 0;
    for (int e = 0; e < 8; ++e) { p[e] = exp(l[e] - mx); s += p[e]; }
    int i1 = 0;
    for (int e = 1; e < 8; ++e) if (p[e] > p[i1]) i1 = e;
    int i2 = (i1 == 0) ? 1 : 0;
    for (int e = 0; e < 8; ++e)
      if (e != i1 && p[e] > p[i2]) i2 = e;
    e01[2 * b] = i1; e01[2 * b + 1] = i2;
    w01[2 * b] = (float)(p[i1] / s);
    w01[2 * b + 1] = (float)(p[i2] / s);
    atomicAdd(&meta[M_CNT + i1], 1);
    atomicAdd(&meta[M_CNT + i2], 1);
  }
}

// Wave-parallel scan, 256-row tile granularity.
__global__ __launch_bounds__(128) void scan_kernel(int* meta) {
  __shared__ int scnt[8];
  int t = threadIdx.x;
  if (t < 8) scnt[t] = meta[M_CNT + t];
  __syncthreads();
  int seg[9], pre[9];
  seg[0] = 0; pre[0] = 0;
#pragma unroll
  for (int e = 0; e < 8; ++e) {
    seg[e + 1] = seg[e] + scnt[e];
    pre[e + 1] = pre[e] + ((scnt[e] + 255) >> 8);
  }
  if (t < 8) meta[M_SEG + t] = seg[t];
  if (t < MAX_TILES) {
    if (t < pre[8]) {
      int e = 0;
      while (e < 7 && t >= pre[e + 1]) ++e;
      int i = t - pre[e];
      meta[M_TE + t] = e;
      meta[M_TB + t] = seg[e] + i * 256;
      meta[M_TR + t] = scnt[e] - i * 256;
    } else {
      meta[M_TE + t] = 0; meta[M_TB + t] = 0; meta[M_TR + t] = 0;
    }
  }
}

__global__ __launch_bounds__(256) void build_kernel(
    const int* __restrict__ e01, const float* __restrict__ w01,
    int* __restrict__ meta, int* __restrict__ rows, float* __restrict__ wt,
    int* __restrict__ rowpos) {
  int b = blockIdx.x * 256 + threadIdx.x;
  if (b >= B_ROWS) return;
#pragma unroll
  for (int s = 0; s < 2; ++s) {
    int e = e01[2 * b + s];
    float w = w01[2 * b + s];
    int p = meta[M_SEG + e] + atomicAdd(&meta[M_FILL + e], 1);
    rows[p] = b;
    wt[p] = w;
    rowpos[2 * b + s] = p;
  }
}

// ---------------------------------------------------------------------------
// 256x256 8-phase MFMA GEMM — R2-exact schedule; B in K-blocked layout
// [e][kt][n][64k]: per K-step the staged B panel is one contiguous 32KB
// stream (was 128B @ 4KB-stride scatter). Byte content per chunk identical.
// ---------------------------------------------------------------------------
#define BAR()                           \
  do {                                  \
    __builtin_amdgcn_sched_barrier(0);  \
    __builtin_amdgcn_s_barrier();       \
    __builtin_amdgcn_sched_barrier(0);  \
  } while (0)
#define VMCNT2() asm volatile("s_waitcnt vmcnt(2)" ::: "memory")
#define VMCNT0() asm volatile("s_waitcnt vmcnt(0)" ::: "memory")
#define LGKM0()                                       \
  do {                                                \
    asm volatile("s_waitcnt lgkmcnt(0)" ::: "memory"); \
    __builtin_amdgcn_sched_barrier(0);                \
  } while (0)

#define STAGE_A(L, T, BB) async16(&lds[BB][0][(L)*4096 + t * 8], srcA[L] + (size_t)(T)*64)
#define STAGE_B(L, T, BB) async16(&lds[BB][1][(L)*4096 + t * 8], srcB[L] + (size_t)(T)*KBLK)

#define READ_A(QM)                                                   \
  do {                                                               \
    _Pragma("unroll") for (int i_ = 0; i_ < 4; ++i_) {               \
      int rb_ = baseA + ((QM)*64 + i_ * 16) * 128;                   \
      af[i_][0] = *(const bf16x8*)(pA + rb_ + ck0);                  \
      af[i_][1] = *(const bf16x8*)(pA + rb_ + ck1);                  \
    }                                                                \
  } while (0)
#define READ_B(H)                                                    \
  do {                                                               \
    _Pragma("unroll") for (int j_ = 0; j_ < 2; ++j_) {               \
      int rb_ = baseB + (((H)*2 + j_) * 16) * 128;                   \
      bfr[(H)*2 + j_][0] = *(const bf16x8*)(pB + rb_ + ck0);         \
      bfr[(H)*2 + j_][1] = *(const bf16x8*)(pB + rb_ + ck1);         \
    }                                                                \
  } while (0)
#define MFMA16(QM, QN)                                                         \
  do {                                                                         \
    _Pragma("unroll") for (int i_ = 0; i_ < 4; ++i_) {                         \
      _Pragma("unroll") for (int j_ = 0; j_ < 2; ++j_) {                       \
        acc[(QM)*4 + i_][(QN)*2 + j_] = __builtin_amdgcn_mfma_f32_16x16x32_bf16( \
            af[i_][0], bfr[(QN)*2 + j_][0], acc[(QM)*4 + i_][(QN)*2 + j_], 0, 0, 0); \
        acc[(QM)*4 + i_][(QN)*2 + j_] = __builtin_amdgcn_mfma_f32_16x16x32_bf16( \
            af[i_][1], bfr[(QN)*2 + j_][1], acc[(QM)*4 + i_][(QN)*2 + j_], 0, 0, 0); \
      }                                                                        \
    }                                                                          \
  } while (0)

template <int MODE>
__global__ __launch_bounds__(512, 2) void gemm256_kernel(
    const u16* __restrict__ A, const u16* __restrict__ BT,
    const int* __restrict__ meta, const int* __restrict__ rows,
    const float* __restrict__ wt, const float* __restrict__ bias,
    u16* __restrict__ Yc, float* __restrict__ Out) {
  __shared__ __align__(16) u16 lds[2][2][16384];  // [buf][A/B][256*64]

  int e = 0, base = 0, rem = 256, m0 = 0;
  if (MODE == 0) {
    rem = meta[M_TR + blockIdx.y];
    if (rem <= 0) return;
    if (rem > 256) rem = 256;
    e = meta[M_TE + blockIdx.y];
    base = meta[M_TB + blockIdx.y];
  } else {
    m0 = blockIdx.y * 256;
  }
  const int n0 = blockIdx.x * 256;
  const int t = threadIdx.x;
  const int lane = t & 63;
  const int wid = t >> 6;
  const int wr = wid >> 2, wc = wid & 3;
  const int l15 = lane & 15;
  const int kg = lane >> 4;
  const int sw = lane & 7;

  const u16* srcA[4];
  const u16* srcB[4];
#pragma unroll
  for (int L = 0; L < 4; ++L) {
    int row = L * 64 + (t >> 3);
    int cl = (t & 7) ^ (row & 7);
    int grow;
    if (MODE == 0) {
      int rl = row < rem ? row : 0;
      grow = rows[base + rl];
    } else {
      grow = m0 + row;
    }
    srcA[L] = A + (size_t)grow * DDIM + cl * 8;
    // Blocked B: panel kt=0 base; STAGE_B steps by T*KBLK.
    srcB[L] = BT + (size_t)e * DDIM * DDIM + (size_t)(n0 + row) * 64 + cl * 8;
  }

  f32x4 acc[8][4];
#pragma unroll
  for (int i = 0; i < 8; ++i)
#pragma unroll
    for (int j = 0; j < 4; ++j) {
      f32x4 z = {0.f, 0.f, 0.f, 0.f};
      acc[i][j] = z;
    }

  const int baseA = (wr * 128 + l15) * 128;
  const int baseB = (wc * 64 + l15) * 128;
  const int ck0 = ((0 * 4 + kg) ^ sw) << 4;
  const int ck1 = ((1 * 4 + kg) ^ sw) << 4;

  bf16x8 af[4][2];
  bf16x8 bfr[4][2];

  STAGE_A(0, 0, 0); STAGE_A(1, 0, 0); STAGE_A(2, 0, 0); STAGE_A(3, 0, 0);
  STAGE_B(0, 0, 0); STAGE_B(1, 0, 0); STAGE_B(2, 0, 0); STAGE_B(3, 0, 0);
  STAGE_A(0, 1, 1); STAGE_A(1, 1, 1);
  VMCNT2();
  BAR();

  const int NT = DDIM / 64;
  for (int T = 0; T < NT; ++T) {
    const int cb = T & 1, nb = cb ^ 1;
    const char* pA = (const char*)&lds[cb][0][0];
    const char* pB = (const char*)&lds[cb][1][0];
    READ_A(0);
    READ_B(0);
    if (T + 1 < NT) { STAGE_A(2, T + 1, nb); STAGE_A(3, T + 1, nb); }
    BAR();
    LGKM0();
    __builtin_amdgcn_s_setprio(1);
    MFMA16(0, 0);
    __builtin_amdgcn_s_setprio(0);
    BAR();
    READ_B(1);
    if (T + 1 < NT) { STAGE_B(0, T + 1, nb); STAGE_B(1, T + 1, nb); }
    BAR();
    LGKM0();
    __builtin_amdgcn_s_setprio(1);
    MFMA16(0, 1);
    __builtin_amdgcn_s_setprio(0);
    BAR();
    READ_A(1);
    if (T + 1 < NT) { STAGE_B(2, T + 1, nb); STAGE_B(3, T + 1, nb); }
    BAR();
    LGKM0();
    __builtin_amdgcn_s_setprio(1);
    MFMA16(1, 0);
    __builtin_amdgcn_s_setprio(0);
    BAR();
    if (T + 2 < NT) {
      STAGE_A(0, T + 2, cb); STAGE_A(1, T + 2, cb);
      VMCNT2();
    } else {
      VMCNT0();
    }
    BAR();
    __builtin_amdgcn_s_setprio(1);
    MFMA16(1, 1);
    __builtin_amdgcn_s_setprio(0);
    BAR();
  }

  if (MODE == 1) {
    float bv[4];
#pragma unroll
    for (int fn = 0; fn < 4; ++fn) bv[fn] = bias[n0 + wc * 64 + fn * 16 + l15];
#pragma unroll
    for (int qm = 0; qm < 2; ++qm)
#pragma unroll
      for (int i = 0; i < 4; ++i)
#pragma unroll
        for (int r = 0; r < 4; ++r) {
          int rl = wr * 128 + qm * 64 + i * 16 + kg * 4 + r;
          float* orow = Out + (size_t)(m0 + rl) * DDIM + n0 + wc * 64 + l15;
#pragma unroll
          for (int fn = 0; fn < 4; ++fn)
            orow[fn * 16] = acc[qm * 4 + i][fn][r] + bv[fn];
        }
  } else {
#pragma unroll
    for (int qm = 0; qm < 2; ++qm)
#pragma unroll
      for (int i = 0; i < 4; ++i)
#pragma unroll
        for (int r = 0; r < 4; ++r) {
          int rl = wr * 128 + qm * 64 + i * 16 + kg * 4 + r;
          if (rl < rem) {
            int pos = base + rl;
            float w = wt[pos];
            u16* yrow = Yc + (size_t)pos * DDIM + n0 + wc * 64 + l15;
#pragma unroll
            for (int fn = 0; fn < 4; ++fn)
              yrow[fn * 16] = f2b(w * acc[qm * 4 + i][fn][r]);
          }
        }
  }
}

// ---------------------------------------------------------------------------
// Combine + 16x16 self-attention per row, MFMA version (R9-exact).
// ---------------------------------------------------------------------------
__global__ __launch_bounds__(64) void combine_attn_kernel(
    const u16* __restrict__ Yc, const int* __restrict__ rowpos,
    u16* __restrict__ ab) {
  __shared__ __align__(16) u16 sb[16][136];
  __shared__ __align__(16) u16 pl[16][20];
  const int b = blockIdx.x, l = threadIdx.x;
  const int p0 = rowpos[2 * b], p1 = rowpos[2 * b + 1];
  const uint4* r0 = (const uint4*)(Yc + (size_t)p0 * DDIM + l * 32);
  const uint4* r1 = (const uint4*)(Yc + (size_t)p1 * DDIM + l * 32);
  {
    const int h = l >> 2, cbase = (l & 3) * 32;
#pragma unroll
    for (int q = 0; q < 4; ++q) {
      uint4 a = r0[q], c = r1[q];
      const unsigned* au = (const unsigned*)&a;
      const unsigned* cu = (const unsigned*)&c;
      uint4 w;
      unsigned* wu = (unsigned*)&w;
#pragma unroll
      for (int j = 0; j < 4; ++j) {
        float lo = b2f((u16)(au[j] & 0xffff)) + b2f((u16)(cu[j] & 0xffff));
        float hi = b2f((u16)(au[j] >> 16)) + b2f((u16)(cu[j] >> 16));
        wu[j] = (unsigned)f2b(lo) | ((unsigned)f2b(hi) << 16);
      }
      *(uint4*)&sb[h][cbase + q * 8] = w;
    }
  }
  __syncthreads();
  const int hh = l & 15, kg = l >> 4;
  f32x4 S = {0.f, 0.f, 0.f, 0.f};
#pragma unroll
  for (int kc = 0; kc < 4; ++kc) {
    bf16x8 f = *(const bf16x8*)&sb[hh][kc * 32 + kg * 8];
    S = __builtin_amdgcn_mfma_f32_16x16x32_bf16(f, f, S, 0, 0, 0);
  }
  const float sc = 0.088388347648318447f;
  float lg[4];
  float mx = -1e30f;
#pragma unroll
  for (int r = 0; r < 4; ++r) { lg[r] = S[r] * sc; mx = fmaxf(mx, lg[r]); }
  mx = fmaxf(mx, __shfl_xor(mx, 16));
  mx = fmaxf(mx, __shfl_xor(mx, 32));
  float p[4], sum = 0.f;
#pragma unroll
  for (int r = 0; r < 4; ++r) { p[r] = expf(lg[r] - mx); sum += p[r]; }
  sum += __shfl_xor(sum, 16);
  sum += __shfl_xor(sum, 32);
  const float inv = 1.f / sum;
#pragma unroll
  for (int r = 0; r < 4; ++r) pl[hh][kg * 4 + r] = f2b(p[r] * inv);
  __syncthreads();
  bf16x8 pa = {0, 0, 0, 0, 0, 0, 0, 0};
  if (kg < 2) pa = *(const bf16x8*)&pl[hh][kg * 8];
  u16* orow = ab + (size_t)b * DDIM;
#pragma unroll
  for (int c = 0; c < 8; ++c) {
    bf16x8 bv = {0, 0, 0, 0, 0, 0, 0, 0};
    if (kg < 2) {
      u16* bvp = (u16*)&bv;
#pragma unroll
      for (int j = 0; j < 8; ++j) bvp[j] = sb[kg * 8 + j][c * 16 + hh];
    }
    f32x4 z = {0.f, 0.f, 0.f, 0.f};
    f32x4 o = __builtin_amdgcn_mfma_f32_16x16x32_bf16(pa, bv, z, 0, 0, 0);
    uint2 st;
    st.x = (unsigned)f2b(o[0]) | ((unsigned)f2b(o[1]) << 16);
    st.y = (unsigned)f2b(o[2]) | ((unsigned)f2b(o[3]) << 16);
    *(uint2*)(orow + (c * 16 + hh) * 16 + kg * 4) = st;
  }
}

extern "C" void kernel_launch(void* const* d_in, const int* in_sizes, int n_in,
                              void* d_out, int out_size, void* d_ws, size_t ws_size,
                              hipStream_t stream) {
  const float* x = (const float*)d_in[0];
  const float* Wqkv = (const float*)d_in[1];
  const float* Wg = (const float*)d_in[2];
  const float* bg = (const float*)d_in[3];
  const float* Wp = (const float*)d_in[4];
  const float* bp = (const float*)d_in[5];
  float* out = (float*)d_out;

  char* ws = (char*)d_ws;
  size_t off = 0;
  auto alloc = [&](size_t bytes) {
    void* p = ws + off;
    off += (bytes + 255) & ~(size_t)255;
    return p;
  };
  u16* xb = (u16*)alloc((size_t)B_ROWS * DDIM * 2);
  u16* WsumT = (u16*)alloc((size_t)NEXP * DDIM * DDIM * 2);
  u16* WprojT = (u16*)alloc((size_t)DDIM * DDIM * 2);
  u16* Yc = (u16*)alloc((size_t)NASSIGN * DDIM * 2);
  u16* ab = (u16*)alloc((size_t)B_ROWS * DDIM * 2);
  int* e01 = (int*)alloc((size_t)NASSIGN * 4);
  float* w01 = (float*)alloc((size_t)NASSIGN * 4);
  int* rows = (int*)alloc((size_t)NASSIGN * 4);
  float* wt = (float*)alloc((size_t)NASSIGN * 4);
  int* rowpos = (int*)alloc((size_t)NASSIGN * 4);
  int* meta = (int*)alloc(4096);

  init_meta_kernel<<<dim3(1), dim3(64), 0, stream>>>(meta);
  prologue_kernel<<<dim3(17408), dim3(256), 0, stream>>>(
      x, Wqkv, Wg, bg, Wp, xb, WsumT, WprojT, e01, w01, meta);
  scan_kernel<<<dim3(1), dim3(128), 0, stream>>>(meta);
  build_kernel<<<dim3(32), dim3(256), 0, stream>>>(e01, w01, meta, rows, wt, rowpos);
  gemm256_kernel<0><<<dim3(8, MAX_TILES), dim3(512), 0, stream>>>(
      xb, WsumT, meta, rows, wt, nullptr, Yc, nullptr);
  combine_attn_kernel<<<dim3(B_ROWS), dim3(64), 0, stream>>>(Yc, rowpos, ab);
  gemm256_kernel<1><<<dim3(8, 32), dim3(512), 0, stream>>>(
      ab, WprojT, meta, rows, wt, bp, nullptr, out);
  (void)in_sizes; (void)n_in; (void)out_size; (void)ws_size;
}